// Round 10
// baseline (413.462 us; speedup 1.0000x reference)
//
#include <hip/hip_runtime.h>
#include <float.h>

#define NN 50000
#define NE 800000
#define NG 64
#define CAP 64
#define EPT 16   // edges per thread in k_count

typedef __attribute__((ext_vector_type(8))) _Float16 f16x8;
typedef __attribute__((ext_vector_type(4))) float f32x4;
typedef __attribute__((ext_vector_type(4))) _Float16 half4;
typedef unsigned int u32;
typedef unsigned short u16;

// ---------- helpers ----------
__device__ __forceinline__ unsigned f2mono(float f) {
  unsigned b = __float_as_uint(f);
  return (b & 0x80000000u) ? ~b : (b | 0x80000000u);
}
__device__ __forceinline__ float mono2f(unsigned u) {
  unsigned b = (u & 0x80000000u) ? (u & 0x7fffffffu) : ~u;
  return __uint_as_float(b);
}
// async global->LDS 16B DMA (gfx950). LDS dest must be wave-uniform base + lane*16.
__device__ __forceinline__ void gl_lds16(const void* g, void* l) {
  __builtin_amdgcn_global_load_lds((const __attribute__((address_space(1))) u32*)g,
                                   (__attribute__((address_space(3))) u32*)l, 16, 0, 0);
}

// ---------- degree count + ELL fill, XCD-partitioned (r6 proven: 44->~10MB wr) ----------
__global__ __launch_bounds__(256) void k_count(const int* __restrict__ src,
                                               const int* __restrict__ dst,
                                               int* __restrict__ cnt,
                                               u16* __restrict__ col) {
  int s = blockIdx.x & 7;
  int base = (blockIdx.x >> 3) * (256 * EPT) + threadIdx.x;
#pragma unroll
  for (int r = 0; r < EPT; ++r) {
    int e = base + r * 256;
    if (e >= NE) break;
    int d = dst[e];
    if ((d & 7) != s) continue;
    if ((unsigned)d >= NN) continue;
    int sv = src[e];
    if ((unsigned)sv >= NN) continue;
    int pos = atomicAdd(&cnt[d], 1);
    if (pos < CAP) col[d * CAP + pos] = (u16)sv;
  }
}

// dinv + pre-scaled input features xs = x * dinv[v]; also zero-init pool buffer
__global__ void k_dinv(const int* __restrict__ cnt, float* __restrict__ dinv,
                       const float* __restrict__ x, float* __restrict__ xs,
                       unsigned* __restrict__ g) {
  int v = blockIdx.x * blockDim.x + threadIdx.x;
  if (v >= NN) return;
  if (v < NG * 256) g[v] = 0u;
  float d = rsqrtf((float)cnt[v] + 1.0f);
  dinv[v] = d;
#pragma unroll
  for (int i = 0; i < 9; ++i) xs[v * 9 + i] = x[v * 9 + i] * d;
}

// ---------- fused weight split+transpose for W2,W3,W4: W[K][Nc] -> Wh/Wl[Nc][K] ----------
__device__ __forceinline__ void splitw1(const float* W, _Float16* Wh, _Float16* Wl,
                                        int i, int K, int Nc) {
  int k = i / Nc, n = i - k * Nc;
  float w = W[i];
  _Float16 h = (_Float16)w;
  _Float16 l = (_Float16)(w - (float)h);
  Wh[(size_t)n * K + k] = h;
  Wl[(size_t)n * K + k] = l;
}
__global__ void k_splitw3(const float* __restrict__ W2, const float* __restrict__ W3,
                          const float* __restrict__ W4,
                          _Float16* __restrict__ W2h, _Float16* __restrict__ W2l,
                          _Float16* __restrict__ W3h, _Float16* __restrict__ W3l,
                          _Float16* __restrict__ W4h, _Float16* __restrict__ W4l) {
  int i = blockIdx.x * 256 + threadIdx.x;
  const int n2 = 128 * 256, n3 = 256 * 256;
  if (i < n2) splitw1(W2, W2h, W2l, i, 128, 256);
  else if (i < n2 + n3) splitw1(W3, W3h, W3l, i - n2, 256, 256);
  else if (i < n2 + 2 * n3) splitw1(W4, W4h, W4l, i - n2 - n3, 256, 256);
}

// ---------- FUSED layer 1: agg9 gather + GEMM 9->128 (+bias, relu, *dinv) ----------
// 3125 blocks x 256 thr; 16 nodes/block (50000 = 16*3125 exactly -> uniform barriers).
__global__ __launch_bounds__(256) void k_l1(const float* __restrict__ xs,
                                            const float* __restrict__ W,
                                            const float* __restrict__ bias,
                                            const float* __restrict__ dinv,
                                            const int* __restrict__ cnt,
                                            const u16* __restrict__ col,
                                            _Float16* __restrict__ out) {
  __shared__ float sW[9 * 128];
  __shared__ float sb[128];
  __shared__ float sX[16][12];      // 9 used, padded
  int t = threadIdx.x;
  if (t < 128) sb[t] = bias[t];
  for (int i = t; i < 9 * 128; i += 256) sW[i] = W[i];
  // gather phase
  int g = t >> 4, l = t & 15;
  int v = blockIdx.x * 16 + g;      // always < NN (exact tiling)
  int c = cnt[v]; if (c > CAP) c = CAP;
  const u16* cl = col + (size_t)v * CAP;
  float acc = (l < 9) ? xs[v * 9 + l] : 0.0f;
  int j = 0;
  for (; j + 4 <= c; j += 4) {
    ushort4 u = *(const ushort4*)(cl + j);
    float a0 = (l < 9) ? xs[(int)u.x * 9 + l] : 0.f;
    float a1 = (l < 9) ? xs[(int)u.y * 9 + l] : 0.f;
    float a2 = (l < 9) ? xs[(int)u.z * 9 + l] : 0.f;
    float a3 = (l < 9) ? xs[(int)u.w * 9 + l] : 0.f;
    acc += (a0 + a1) + (a2 + a3);
  }
  for (; j < c; ++j) {
    int u = cl[j];
    if (l < 9) acc += xs[u * 9 + l];
  }
  if (l < 9) sX[g][l] = acc * dinv[v];
  __syncthreads();
  // gemm phase
  int cc = t & 127;
  int g0 = (t >> 7) * 8;
#pragma unroll
  for (int rr = 0; rr < 8; ++rr) {
    int gi = g0 + rr;
    int r = blockIdx.x * 16 + gi;
    float a = sb[cc];
#pragma unroll
    for (int i = 0; i < 9; ++i) a += sX[gi][i] * sW[i * 128 + cc];
    out[(size_t)r * 128 + cc] = (_Float16)(fmaxf(a, 0.0f) * dinv[r]);
  }
}

// ---------- XCD-sliced aggregation, 4-deep (r6 proven best: 58.0 us @F=256) ----------
// F=256 gather pinned ~58 us across 4 structural variants -> fabric floor; lane closed.
__global__ __launch_bounds__(256) void k_aggs(const half4* __restrict__ h,
                                              half4* __restrict__ out,
                                              const int* __restrict__ cnt,
                                              const u16* __restrict__ col,
                                              const float* __restrict__ dinv,
                                              int rowU, int slog) {
  int bid = blockIdx.x;
  int s = bid & ((1 << slog) - 1);
  int chunk = bid >> slog;
  int g = threadIdx.x >> 4;
  int l = threadIdx.x & 15;
  int v = chunk * 16 + g;
  if (v >= NN) return;
  int so = s * 16 + l;                 // half4 offset within row
  int c = cnt[v]; if (c > CAP) c = CAP;
  const u16* cl = col + (size_t)v * CAP;
  half4 sv = h[(size_t)v * rowU + so];
  float ax = (float)sv.x, ay = (float)sv.y, az = (float)sv.z, aw = (float)sv.w;
  int j = 0;
  for (; j + 4 <= c; j += 4) {
    ushort4 u = *(const ushort4*)(cl + j);
    half4 t0 = h[(size_t)u.x * rowU + so];
    half4 t1 = h[(size_t)u.y * rowU + so];
    half4 t2 = h[(size_t)u.z * rowU + so];
    half4 t3 = h[(size_t)u.w * rowU + so];
    ax += ((float)t0.x + (float)t1.x) + ((float)t2.x + (float)t3.x);
    ay += ((float)t0.y + (float)t1.y) + ((float)t2.y + (float)t3.y);
    az += ((float)t0.z + (float)t1.z) + ((float)t2.z + (float)t3.z);
    aw += ((float)t0.w + (float)t1.w) + ((float)t2.w + (float)t3.w);
  }
  for (; j < c; ++j) {
    half4 tv = h[(size_t)cl[j] * rowU + so];
    ax += (float)tv.x; ay += (float)tv.y; az += (float)tv.z; aw += (float)tv.w;
  }
  float d = dinv[v];
  half4 o;
  o.x = (_Float16)(ax * d); o.y = (_Float16)(ay * d);
  o.z = (_Float16)(az * d); o.w = (_Float16)(aw * d);
  out[(size_t)v * rowU + so] = o;
}

// ---------- MFMA fp16 hi/lo-weight GEMM, Bh/Bl TIME-SHARED LDS (32 KB) ----------
// r9 diagnosis: mm ~60-70us/dispatch, latency-bound at 3 blocks/CU (48KB LDS).
// Fix: stage Bh and Bl sequentially through ONE 16KB buffer -> 32KB total ->
// 4-5 blocks/CU (16-20 waves). Per K-step: sync; stage A+Bh; sync; MFMA-hi;
// sync; stage Bl; sync; MFMA-lo. Staging swizzle + read decode byte-identical
// to the r0 proven form; va re-read from LDS in the lo phase (keeps VGPR low).
__global__ __launch_bounds__(256, 4) void k_mm(const _Float16* __restrict__ A,
                                               const _Float16* __restrict__ Bh,
                                               const _Float16* __restrict__ Bl,
                                               const float* __restrict__ bias,
                                               _Float16* __restrict__ C,
                                               const float* __restrict__ dinv,
                                               const int* __restrict__ batch,
                                               unsigned* __restrict__ gpool,
                                               int M, int K, int Nc, int mode) {
  __shared__ __align__(16) _Float16 Alds[128 * 64];   // 16 KB
  __shared__ __align__(16) _Float16 Bbuf[128 * 64];   // 16 KB, time-shared hi/lo
  int bid = blockIdx.x;
  int rblk = (bid >> 4) * 8 + (bid & 7);
  int cblk = (bid >> 3) & 1;
  if (rblk * 128 >= M) return;
  int rowBase = rblk * 128;
  int colBase = cblk * 128;
  int t = threadIdx.x;
  int wave = t >> 6, lane = t & 63;
  int wm = wave & 1, wn = wave >> 1;
  int lm = lane & 15;
  int q  = lane >> 4;

  int srl = wave * 32 + (lane >> 3);
  int sj  = lane & 7;
  int ssw = lane >> 3;
  int gseg = sj ^ ssw;

  f32x4 acc[4][4];
#pragma unroll
  for (int i = 0; i < 4; ++i)
#pragma unroll
    for (int j = 0; j < 4; ++j) acc[i][j] = (f32x4){0.f, 0.f, 0.f, 0.f};

  int nit = K >> 6;
  for (int it = 0; it < nit; ++it) {
    __syncthreads();                       // prev MFMA-lo done with Alds/Bbuf
#pragma unroll
    for (int c = 0; c < 4; ++c) {
      int rl = srl + c * 8;
      int ga = rowBase + rl; if (ga > M - 1) ga = M - 1;
      int gb = colBase + rl;
      unsigned off = (unsigned)it * 64 + gseg * 8;
      int ldst = (wave * 32 + c * 8) * 64 + lane * 8;
      gl_lds16(A  + (size_t)ga * K + off, Alds + ldst);
      gl_lds16(Bh + (size_t)gb * K + off, Bbuf + ldst);
    }
    __syncthreads();                       // A + Bh visible

    // MFMA-hi
#pragma unroll
    for (int s2 = 0; s2 < 2; ++s2) {
      int slotq = ((s2 << 2) | q);
      int slot = slotq ^ (lm & 7);
      f16x8 vb[4];
#pragma unroll
      for (int ni = 0; ni < 4; ++ni)
        vb[ni] = *(const f16x8*)(Bbuf + (wn * 64 + ni * 16 + lm) * 64 + slot * 8);
#pragma unroll
      for (int mi = 0; mi < 4; ++mi) {
        f16x8 va = *(const f16x8*)(Alds + (wm * 64 + mi * 16 + lm) * 64 + slot * 8);
#pragma unroll
        for (int ni = 0; ni < 4; ++ni)
          acc[mi][ni] = __builtin_amdgcn_mfma_f32_16x16x32_f16(va, vb[ni], acc[mi][ni], 0, 0, 0);
      }
    }
    __syncthreads();                       // hi done reading Bbuf

#pragma unroll
    for (int c = 0; c < 4; ++c) {
      int rl = srl + c * 8;
      int gb = colBase + rl;
      unsigned off = (unsigned)it * 64 + gseg * 8;
      int ldst = (wave * 32 + c * 8) * 64 + lane * 8;
      gl_lds16(Bl + (size_t)gb * K + off, Bbuf + ldst);
    }
    __syncthreads();                       // Bl visible

    // MFMA-lo (A still valid in Alds)
#pragma unroll
    for (int s2 = 0; s2 < 2; ++s2) {
      int slotq = ((s2 << 2) | q);
      int slot = slotq ^ (lm & 7);
      f16x8 vb[4];
#pragma unroll
      for (int ni = 0; ni < 4; ++ni)
        vb[ni] = *(const f16x8*)(Bbuf + (wn * 64 + ni * 16 + lm) * 64 + slot * 8);
#pragma unroll
      for (int mi = 0; mi < 4; ++mi) {
        f16x8 va = *(const f16x8*)(Alds + (wm * 64 + mi * 16 + lm) * 64 + slot * 8);
#pragma unroll
        for (int ni = 0; ni < 4; ++ni)
          acc[mi][ni] = __builtin_amdgcn_mfma_f32_16x16x32_f16(va, vb[ni], acc[mi][ni], 0, 0, 0);
      }
    }
  }

  int rowOff = (lane >> 4) * 4;
  if (mode == 2) {
    __syncthreads();
    unsigned* ldsPool = (unsigned*)Alds;
    for (int i = t; i < 4 * 256; i += 256) ldsPool[i] = 0u;
    __syncthreads();
    int b0 = batch[rowBase];
#pragma unroll
    for (int mi = 0; mi < 4; ++mi) {
#pragma unroll
      for (int ni = 0; ni < 4; ++ni) {
        int gc = colBase + wn * 64 + ni * 16 + lm;
        float bsv = bias[gc];
#pragma unroll
        for (int r = 0; r < 4; ++r) {
          int gr = rowBase + wm * 64 + mi * 16 + rowOff + r;
          if (gr < M) {
            float v = acc[mi][ni][r] + bsv;
            int idx = batch[gr] - b0;
            if (idx < 0) idx = 0;
            if (idx > 3) idx = 3;
            atomicMax(&ldsPool[idx * 256 + gc], f2mono(v));
          }
        }
      }
    }
    __syncthreads();
#pragma unroll
    for (int s4 = 0; s4 < 4; ++s4) {
      unsigned mv = ldsPool[s4 * 256 + t];
      int gb = b0 + s4;
      if (mv && gb < NG) atomicMax(&gpool[gb * 256 + t], mv);
    }
  } else {
#pragma unroll
    for (int mi = 0; mi < 4; ++mi) {
#pragma unroll
      for (int ni = 0; ni < 4; ++ni) {
        int gc = colBase + wn * 64 + ni * 16 + lm;
        float bsv = bias[gc];
#pragma unroll
        for (int r = 0; r < 4; ++r) {
          int gr = rowBase + wm * 64 + mi * 16 + rowOff + r;
          if (gr < M) {
            float v = fmaxf(acc[mi][ni][r] + bsv, 0.0f);
            C[(size_t)gr * Nc + gc] = (_Float16)(v * dinv[gr]);
          }
        }
      }
    }
  }
}

// ---------- dense head ----------
__global__ __launch_bounds__(256) void k_head(const unsigned* __restrict__ g,
                                              const float* __restrict__ Wl2, const float* __restrict__ bl2,
                                              const float* __restrict__ Wl3, const float* __restrict__ bl3,
                                              const float* __restrict__ Wl, const float* __restrict__ bl,
                                              float* __restrict__ out) {
  __shared__ float s0[256];
  __shared__ float s1[128];
  __shared__ float s2[128];
  int b = blockIdx.x, t = threadIdx.x;
  s0[t] = mono2f(g[b * 256 + t]);
  __syncthreads();
  if (t < 128) {
    float acc = bl2[t];
    for (int k = 0; k < 256; ++k) acc += s0[k] * Wl2[k * 128 + t];
    s1[t] = fmaxf(acc, 0.0f);
  }
  __syncthreads();
  if (t < 128) {
    float acc = bl3[t];
    for (int k = 0; k < 128; ++k) acc += s1[k] * Wl3[k * 128 + t];
    s2[t] = fmaxf(acc, 0.0f);
  }
  __syncthreads();
  if (t < 10) {
    float acc = bl[t];
    for (int k = 0; k < 128; ++k) acc += s2[k] * Wl[k * 10 + t];
    out[b * 10 + t] = acc;
  }
}

extern "C" void kernel_launch(void* const* d_in, const int* in_sizes, int n_in,
                              void* d_out, int out_size, void* d_ws, size_t ws_size,
                              hipStream_t stream) {
  const float* x   = (const float*)d_in[0];
  const int* eidx  = (const int*)d_in[1];
  const int* batch = (const int*)d_in[2];
  const float* W1 = (const float*)d_in[3];   const float* b1 = (const float*)d_in[4];
  const float* W2 = (const float*)d_in[5];   const float* b2 = (const float*)d_in[6];
  const float* W3 = (const float*)d_in[7];   const float* b3 = (const float*)d_in[8];
  const float* W4 = (const float*)d_in[9];   const float* b4 = (const float*)d_in[10];
  const float* Wl2 = (const float*)d_in[11]; const float* bl2 = (const float*)d_in[12];
  const float* Wl3 = (const float*)d_in[13]; const float* bl3 = (const float*)d_in[14];
  const float* Wl  = (const float*)d_in[15]; const float* bl  = (const float*)d_in[16];
  float* out = (float*)d_out;

  // ---- workspace carve ----
  _Float16* bufA = (_Float16*)d_ws;                                // NN*256 fp16
  _Float16* bufB = bufA + (size_t)NN * 256;                        // NN*256 fp16
  int* cnt  = (int*)(bufB + (size_t)NN * 256);                     // NN
  float* dinv = (float*)(cnt + NN);                                // NN
  u16* col  = (u16*)(dinv + NN);                                   // NN*CAP ushort
  unsigned* g = (unsigned*)(col + (size_t)NN * CAP);               // NG*256
  _Float16* W2h = (_Float16*)(g + NG * 256);                       // 256*128
  _Float16* W2l = W2h + 256 * 128;
  _Float16* W3h = W2l + 256 * 128;                                 // 256*256
  _Float16* W3l = W3h + 256 * 256;
  _Float16* W4h = W3l + 256 * 256;
  _Float16* W4l = W4h + 256 * 256;
  float* xs = (float*)bufB;        // NN*9 fp32 in bufB: dead before layer-2 aggs writes bufB

  const int* src = eidx;
  const int* dst = eidx + NE;

  hipMemsetAsync(cnt, 0, NN * sizeof(int), stream);

  const int cntGrid = 8 * ((NE + 256 * EPT - 1) / (256 * EPT));
  k_count<<<cntGrid, 256, 0, stream>>>(src, dst, cnt, col);
  k_dinv<<<(NN + 255) / 256, 256, 0, stream>>>(cnt, dinv, x, xs, g);

  k_splitw3<<<(128 * 256 + 2 * 256 * 256 + 255) / 256, 256, 0, stream>>>(
      W2, W3, W4, W2h, W2l, W3h, W3l, W4h, W4l);

  const int nchunk = (NN + 15) / 16;           // 3125: 16 nodes per block, exact
  const int mmGrid = 784;                      // 392 row-blocks x 2 col-blocks, XCD-paired

  // layer 1: FUSED agg9 + GEMM 9->128 (+relu, *dinv) xs(bufB) -> bufA fp16
  k_l1<<<nchunk, 256, 0, stream>>>(xs, W1, b1, dinv, cnt, col, bufA);

  // layer 2: sliced gather 128-dim bufA->bufB (2 slices), MFMA GEMM 128->256 bufB->bufA
  k_aggs<<<nchunk * 2, 256, 0, stream>>>((const half4*)bufA, (half4*)bufB, cnt, col, dinv, 32, 1);
  k_mm<<<mmGrid, 256, 0, stream>>>(bufB, W2h, W2l, b2, bufA, dinv, batch, g, NN, 128, 256, 1);

  // layer 3: sliced gather 256-dim bufA->bufB (4 slices), GEMM bufB->bufA
  k_aggs<<<nchunk * 4, 256, 0, stream>>>((const half4*)bufA, (half4*)bufB, cnt, col, dinv, 64, 2);
  k_mm<<<mmGrid, 256, 0, stream>>>(bufB, W3h, W3l, b3, bufA, dinv, batch, g, NN, 256, 256, 1);

  // layer 4: sliced gather 256-dim bufA->bufB, GEMM + fused max-pool (no C write)
  k_aggs<<<nchunk * 4, 256, 0, stream>>>((const half4*)bufA, (half4*)bufB, cnt, col, dinv, 64, 2);
  k_mm<<<mmGrid, 256, 0, stream>>>(bufB, W4h, W4l, b4, bufA, dinv, batch, g, NN, 256, 256, 2);

  // head
  k_head<<<NG, 256, 0, stream>>>(g, Wl2, bl2, Wl3, bl3, Wl, bl, out);
}